// Round 5
// baseline (685.705 us; speedup 1.0000x reference)
//
#include <hip/hip_runtime.h>

#define N_BINS 15
#define NCLASS 128

typedef float fx4 __attribute__((ext_vector_type(4)));

__global__ void zero_out_kernel(float* __restrict__ out) {
    int i = threadIdx.x;
    if (i < 2 * N_BINS) out[i] = 0.0f;
}

// Cross-lane butterfly within a 32-lane half-wave.
// xor1/xor2 via DPP quad_perm (VALU pipe); xor4/8/16 via ds_swizzle (bit-mode,
// and=0x1F keeps exchanges inside each 32-lane group).
__device__ __forceinline__ int dpp_xor1_i(int x) {
    return __builtin_amdgcn_mov_dpp(x, 0xB1, 0xF, 0xF, true);  // [1,0,3,2]
}
__device__ __forceinline__ int dpp_xor2_i(int x) {
    return __builtin_amdgcn_mov_dpp(x, 0x4E, 0xF, 0xF, true);  // [2,3,0,1]
}
__device__ __forceinline__ int swz_xor4_i(int x)  { return __builtin_amdgcn_ds_swizzle(x, 0x101F); }
__device__ __forceinline__ int swz_xor8_i(int x)  { return __builtin_amdgcn_ds_swizzle(x, 0x201F); }
__device__ __forceinline__ int swz_xor16_i(int x) { return __builtin_amdgcn_ds_swizzle(x, 0x401F); }
__device__ __forceinline__ float dpp_xor1_f(float x)  { return __int_as_float(dpp_xor1_i(__float_as_int(x))); }
__device__ __forceinline__ float dpp_xor2_f(float x)  { return __int_as_float(dpp_xor2_i(__float_as_int(x))); }
__device__ __forceinline__ float swz_xor4_f(float x)  { return __int_as_float(swz_xor4_i(__float_as_int(x))); }
__device__ __forceinline__ float swz_xor8_f(float x)  { return __int_as_float(swz_xor8_i(__float_as_int(x))); }
__device__ __forceinline__ float swz_xor16_f(float x) { return __int_as_float(swz_xor16_i(__float_as_int(x))); }

__global__ __launch_bounds__(256, 4) void conf_hist_kernel(
        const float* __restrict__ logits,
        const int* __restrict__ labels,
        float* __restrict__ out,
        int n) {
    __shared__ int hist[2 * N_BINS];
    if (threadIdx.x < 2 * N_BINS) hist[threadIdx.x] = 0;
    __syncthreads();

    const int lane = threadIdx.x & 63;
    const int half = lane >> 5;   // 0: even row of pair, 1: odd row
    const int c32 = lane & 31;    // position within the 32-lane row group
    const int wavesPerBlock = blockDim.x >> 6;
    const int wave = blockIdx.x * wavesPerBlock + (threadIdx.x >> 6);
    const int numWaves = gridDim.x * wavesPerBlock;
    const int stride = numWaves * 16;  // 16 samples / wave-iteration

    // Load p (p=0..7): lane l reads 16B at logits[(base+2p)*128 + l*4]
    //  -> one perfectly contiguous, 1KB-aligned block (rows base+2p, base+2p+1).
    // Lane l holds cols (l&31)*4 .. +3 of row base+2p+(l>>5).
    // n % 16 == 0 and base % 16 == 0 -> all predicates wave-uniform.
    const float* lanep = logits + lane * 4;

    // ---- prologue: load iteration 0 ----
    int base = wave * 16;
    fx4 cA[8];
    int labA = 0;
    if (base < n) {
        const float* pb = lanep + (size_t)base * NCLASS;
        #pragma unroll
        for (int p = 0; p < 8; ++p) cA[p] = *(const fx4*)(pb + p * 256);
        labA = labels[base + (c32 & 15)];  // lane 2p+32*half holds label of row base+2p? no:
                                           // lane with c32==r holds labels[base+r] in BOTH halves
    }

    for (; base < n; base += stride) {
        // ---- software pipeline: issue NEXT iteration's loads first ----
        const int nbase = base + stride;
        fx4 cB[8];
        int labB = 0;
        if (nbase < n) {
            const float* pb = lanep + (size_t)nbase * NCLASS;
            #pragma unroll
            for (int p = 0; p < 8; ++p) cB[p] = *(const fx4*)(pb + p * 256);
            labB = labels[nbase + (c32 & 15)];
        } else {
            #pragma unroll
            for (int p = 0; p < 8; ++p) cB[p] = (fx4)(0.0f);
        }

        // ---- compute on buffer A (B's loads in flight); 8 independent chains ----
        #pragma unroll
        for (int p = 0; p < 8; ++p) {
            const fx4 v = cA[p];

            // lane-local argmax over 4; strict > keeps lowest index
            float mm = v[0]; int ii = 0;
            if (v[1] > mm) { mm = v[1]; ii = 1; }
            if (v[2] > mm) { mm = v[2]; ii = 2; }
            if (v[3] > mm) { mm = v[3]; ii = 3; }
            float bm = mm; int bi = (c32 << 2) + ii;

            // 32-lane butterfly, tie-break lower column index
            { float om = dpp_xor1_f(bm);  int oi = dpp_xor1_i(bi);
              if (om > bm || (om == bm && oi < bi)) { bm = om; bi = oi; } }
            { float om = dpp_xor2_f(bm);  int oi = dpp_xor2_i(bi);
              if (om > bm || (om == bm && oi < bi)) { bm = om; bi = oi; } }
            { float om = swz_xor4_f(bm);  int oi = swz_xor4_i(bi);
              if (om > bm || (om == bm && oi < bi)) { bm = om; bi = oi; } }
            { float om = swz_xor8_f(bm);  int oi = swz_xor8_i(bi);
              if (om > bm || (om == bm && oi < bi)) { bm = om; bi = oi; } }
            { float om = swz_xor16_f(bm); int oi = swz_xor16_i(bi);
              if (om > bm || (om == bm && oi < bi)) { bm = om; bi = oi; } }

            // sum exp(l - max) across the row
            float e = (__expf(v[0] - bm) + __expf(v[1] - bm))
                    + (__expf(v[2] - bm) + __expf(v[3] - bm));
            e += dpp_xor1_f(e);
            e += dpp_xor2_f(e);
            e += swz_xor4_f(e);
            e += swz_xor8_f(e);
            e += swz_xor16_f(e);

            // atomic lane = the lane whose c32 equals its row's offset (2p+half),
            // so it already owns that row's label in labA — no cross-lane move.
            if (c32 == 2 * p + half) {
                float conf = 1.0f / e;
                int bin = (int)(conf * (float)N_BINS);
                bin = bin > (N_BINS - 1) ? (N_BINS - 1) : (bin < 0 ? 0 : bin);
                int col = (bi == labA) ? 0 : 1;  // col 0: correct
                atomicAdd(&hist[bin * 2 + col], 1);
            }
        }

        // ---- rotate buffers ----
        #pragma unroll
        for (int p = 0; p < 8; ++p) cA[p] = cB[p];
        labA = labB;
    }

    __syncthreads();
    if (threadIdx.x < 2 * N_BINS) {
        int c = hist[threadIdx.x];
        if (c != 0) atomicAdd(&out[threadIdx.x], (float)c);
    }
}

extern "C" void kernel_launch(void* const* d_in, const int* in_sizes, int n_in,
                              void* d_out, int out_size, void* d_ws, size_t ws_size,
                              hipStream_t stream) {
    const float* logits = (const float*)d_in[0];
    const int*   labels = (const int*)d_in[1];
    float* out = (float*)d_out;
    const int n = in_sizes[1];  // number of samples

    zero_out_kernel<<<1, 64, 0, stream>>>(out);

    const int block = 256;
    const int grid = 1024;  // 4096 waves = 4 blocks/CU, exactly resident (VGPR<=128)
    conf_hist_kernel<<<grid, block, 0, stream>>>(logits, labels, out, n);
}

// Round 6
// 629.017 us; speedup vs baseline: 1.0901x; 1.0901x over previous
//
#include <hip/hip_runtime.h>

#define N_BINS 15
#define NCLASS 128

typedef float fx4 __attribute__((ext_vector_type(4)));

__global__ void zero_out_kernel(float* __restrict__ out) {
    int i = threadIdx.x;
    if (i < 2 * N_BINS) out[i] = 0.0f;
}

// DPP quad_perm cross-lane moves (VALU pipe, no LDS/DS latency).
// 0xB1 = [1,0,3,2] (xor 1), 0x4E = [2,3,0,1] (xor 2).
__device__ __forceinline__ int dpp_xor1_i(int x) {
    return __builtin_amdgcn_mov_dpp(x, 0xB1, 0xF, 0xF, true);
}
__device__ __forceinline__ int dpp_xor2_i(int x) {
    return __builtin_amdgcn_mov_dpp(x, 0x4E, 0xF, 0xF, true);
}
__device__ __forceinline__ float dpp_xor1_f(float x) {
    return __int_as_float(dpp_xor1_i(__float_as_int(x)));
}
__device__ __forceinline__ float dpp_xor2_f(float x) {
    return __int_as_float(dpp_xor2_i(__float_as_int(x)));
}

// 8 waves/SIMD: cap VGPR at 64 so all 8192 waves are resident (32 waves/CU).
// TLP (8 interleaved waves) hides load latency instead of a register pipeline.
__global__ __launch_bounds__(256, 8) void conf_hist_kernel(
        const float* __restrict__ logits,
        const int* __restrict__ labels,
        float* __restrict__ out,
        int n) {
    __shared__ int hist[2 * N_BINS];
    if (threadIdx.x < 2 * N_BINS) hist[threadIdx.x] = 0;
    __syncthreads();

    const int lane = threadIdx.x & 63;
    const int quad = lane >> 2;  // 16 quads/wave, one sample each
    const int t = lane & 3;      // position within quad
    const int wavesPerBlock = blockDim.x >> 6;
    const int wave = blockIdx.x * wavesPerBlock + (threadIdx.x >> 6);
    const int numWaves = gridDim.x * wavesPerBlock;
    const int stride = numWaves * 16;

    for (int base = wave * 16; base < n; base += stride) {
        const int s = base + quad;  // n%16==0 -> wave-uniform predicate
        if (s < n) {
            // lane t loads cols j*16 + t*4 .. +3 (64B contiguous per quad per instr)
            const float* row = logits + (size_t)s * NCLASS + t * 4;
            fx4 c[8];
            #pragma unroll
            for (int j = 0; j < 8; ++j)
                c[j] = __builtin_nontemporal_load((const fx4*)(row + j * 16));
            // issue label load now; latency hides under argmax below
            const int lab = labels[s];

            // per-chunk argmax; strict > keeps first (lowest) index
            float m[8]; int mi[8];
            #pragma unroll
            for (int j = 0; j < 8; ++j) {
                float mm = c[j][0]; int ii = 0;
                if (c[j][1] > mm) { mm = c[j][1]; ii = 1; }
                if (c[j][2] > mm) { mm = c[j][2]; ii = 2; }
                if (c[j][3] > mm) { mm = c[j][3]; ii = 3; }
                m[j] = mm; mi[j] = j * 16 + t * 4 + ii;
            }
            // tree 8->1; left operand has lower indices, > keeps left on tie
            #pragma unroll
            for (int stp = 1; stp < 8; stp <<= 1) {
                #pragma unroll
                for (int j = 0; j < 8; j += 2 * stp) {
                    if (m[j + stp] > m[j]) { m[j] = m[j + stp]; mi[j] = mi[j + stp]; }
                }
            }
            float bm = m[0]; int bi = mi[0];

            // quad butterfly via DPP (tie-break by index explicitly)
            {
                float om = dpp_xor1_f(bm); int oi = dpp_xor1_i(bi);
                if (om > bm || (om == bm && oi < bi)) { bm = om; bi = oi; }
            }
            {
                float om = dpp_xor2_f(bm); int oi = dpp_xor2_i(bi);
                if (om > bm || (om == bm && oi < bi)) { bm = om; bi = oi; }
            }

            // sum exp(l - max), pairwise tree
            float s4[8];
            #pragma unroll
            for (int j = 0; j < 8; ++j)
                s4[j] = (__expf(c[j][0] - bm) + __expf(c[j][1] - bm))
                      + (__expf(c[j][2] - bm) + __expf(c[j][3] - bm));
            float e = ((s4[0] + s4[1]) + (s4[2] + s4[3]))
                    + ((s4[4] + s4[5]) + (s4[6] + s4[7]));
            e += dpp_xor1_f(e);
            e += dpp_xor2_f(e);

            if (t == 0) {
                float conf = 1.0f / e;
                int bin = (int)(conf * (float)N_BINS);
                bin = bin > (N_BINS - 1) ? (N_BINS - 1) : (bin < 0 ? 0 : bin);
                int col = (bi == lab) ? 0 : 1;  // col 0: correct
                atomicAdd(&hist[bin * 2 + col], 1);
            }
        }
    }

    __syncthreads();
    if (threadIdx.x < 2 * N_BINS) {
        int c = hist[threadIdx.x];
        if (c != 0) atomicAdd(&out[threadIdx.x], (float)c);
    }
}

extern "C" void kernel_launch(void* const* d_in, const int* in_sizes, int n_in,
                              void* d_out, int out_size, void* d_ws, size_t ws_size,
                              hipStream_t stream) {
    const float* logits = (const float*)d_in[0];
    const int*   labels = (const int*)d_in[1];
    float* out = (float*)d_out;
    const int n = in_sizes[1];  // number of samples

    zero_out_kernel<<<1, 64, 0, stream>>>(out);

    const int block = 256;
    const int grid = 2048;  // 8192 waves, ALL resident at 8 waves/SIMD
    conf_hist_kernel<<<grid, block, 0, stream>>>(logits, labels, out, n);
}